// Round 3
// baseline (80.386 us; speedup 1.0000x reference)
//
#include <hip/hip_runtime.h>

// Problem constants (match reference)
constexpr int B = 8, Q = 900, K = 1203, N = 100;
constexpr float ALPHA = 0.25f, EPS = 1e-8f;
constexpr float COST_CLASS = 2.0f, COST_BBOX = 5.0f, COST_GIOU = 2.0f;

constexpr int NV = 4;            // outputs per thread along n
constexpr int GROUPS = N / NV;   // 25

__global__ __launch_bounds__(256) void matcher_cost_kernel(
    const float* __restrict__ logits,   // (B,Q,K)
    const float* __restrict__ pboxes,   // (B,Q,4) cxcywh
    const int*   __restrict__ labels,   // (B,N)
    const float* __restrict__ tboxes,   // (B,N,4) cxcywh
    float* __restrict__ out)            // (B,Q,N)
{
    int idx = blockIdx.x * blockDim.x + threadIdx.x;
    constexpr int TOTALG = B * Q * GROUPS;   // 180000
    if (idx >= TOTALG) return;

    int ng = idx % GROUPS;
    int bq = idx / GROUPS;       // b*Q + q
    int b  = bq / Q;

    // ---- 4 labels (int4, 16B aligned) + 4 independent logits gathers ----
    const int4 lab4 = *reinterpret_cast<const int4*>(labels + b * N + ng * NV);
    const float* lrow = logits + (size_t)bq * K;
    float x0 = lrow[lab4.x];
    float x1 = lrow[lab4.y];
    float x2 = lrow[lab4.z];
    float x3 = lrow[lab4.w];
    float xs[NV] = {x0, x1, x2, x3};

    // ---- pred box (amortized over 4 outputs) ----
    const float4 pbv = *reinterpret_cast<const float4*>(pboxes + (size_t)bq * 4);
    float pcx = pbv.x, pcy = pbv.y, pw = pbv.z, ph = pbv.w;
    float px1 = pcx - 0.5f * pw, py1 = pcy - 0.5f * ph;
    float px2 = pcx + 0.5f * pw, py2 = pcy + 0.5f * ph;
    float area1 = (px2 - px1) * (py2 - py1);

    // ---- 4 target boxes: 64B contiguous ----
    const float4* tbp = reinterpret_cast<const float4*>(tboxes + ((size_t)b * N + ng * NV) * 4);
    float4 tbv[NV];
#pragma unroll
    for (int j = 0; j < NV; ++j) tbv[j] = tbp[j];

    float4 res;
    float* rp = &res.x;
#pragma unroll
    for (int j = 0; j < NV; ++j) {
        // focal class cost
        float x = xs[j];
        float p   = 1.0f / (1.0f + expf(-x));
        float omp = 1.0f - p;
        float pos = -ALPHA * omp * omp * logf(fmaxf(p, EPS));
        float neg = -(1.0f - ALPHA) * p * p * logf(fmaxf(omp, EPS));
        float cls = pos - neg;

        float tcx = tbv[j].x, tcy = tbv[j].y, tw = tbv[j].z, th = tbv[j].w;

        // L1 in cxcywh space
        float l1 = fabsf(pcx - tcx) + fabsf(pcy - tcy) + fabsf(pw - tw) + fabsf(ph - th);

        // GIoU
        float tx1 = tcx - 0.5f * tw, ty1 = tcy - 0.5f * th;
        float tx2 = tcx + 0.5f * tw, ty2 = tcy + 0.5f * th;
        float area2 = (tx2 - tx1) * (ty2 - ty1);

        float iw = fmaxf(fminf(px2, tx2) - fmaxf(px1, tx1), 0.0f);
        float ih = fmaxf(fminf(py2, ty2) - fmaxf(py1, ty1), 0.0f);
        float inter = iw * ih;
        float uni   = area1 + area2 - inter;
        float iou   = inter / uni;

        float cw = fmaxf(fmaxf(px2, tx2) - fminf(px1, tx1), 0.0f);
        float ch = fmaxf(fmaxf(py2, ty2) - fminf(py1, ty1), 0.0f);
        float areac = cw * ch;
        float giou  = iou - (areac - uni) / areac;

        rp[j] = COST_CLASS * cls + COST_BBOX * l1 - COST_GIOU * giou;
    }

    // coalesced 16B store (out row length 100 floats = 400B, ng*16B offset)
    *reinterpret_cast<float4*>(out + (size_t)bq * N + ng * NV) = res;
}

extern "C" void kernel_launch(void* const* d_in, const int* in_sizes, int n_in,
                              void* d_out, int out_size, void* d_ws, size_t ws_size,
                              hipStream_t stream) {
    const float* logits = (const float*)d_in[0];
    const float* pboxes = (const float*)d_in[1];
    const int*   labels = (const int*)d_in[2];
    const float* tboxes = (const float*)d_in[3];
    float* out = (float*)d_out;

    constexpr int TOTALG = B * Q * GROUPS;    // 180000
    constexpr int BLOCK = 256;
    int grid = (TOTALG + BLOCK - 1) / BLOCK;  // 704
    matcher_cost_kernel<<<grid, BLOCK, 0, stream>>>(logits, pboxes, labels, tboxes, out);
}